// Round 1
// baseline (160.816 us; speedup 1.0000x reference)
//
#include <hip/hip_runtime.h>

// QuantileLoss: mean over [ (p0-t0)^2, (p1-t1)^2, (p2-t2)^2, lower, upper ]
//   lower = p3>p2 ? (p4-t2)*4 : (p3>0.95*t2 ? 0 : (p3-0.95*t2)^2)
//   upper = p4<p2 ? (p4-t2)*4 : (p4<1.05*t2 ? 0 : (p4-1.05*t2)^2)
//
// R1/R2: single-address atomicAdd(double) serialized -> per-block partials.
// R3 (157.4us): wave-private 64-row LDS tiles, zero __syncthreads in hot loop,
//   1-deep register prefetch, 1024 blocks. rocprof: ql_main=50.6us, VALUBusy 7%,
//   Occupancy 31%, bank-conflict 0 -> latency/MLP-bound at 2.65 TB/s effective
//   (134MB roofline @6.3TB/s = 21.3us).
// R4 (this): raise bytes-in-flight per CU ~4x:
//   (a) grid 1024 -> 2048 blocks = 8 blocks/CU = 32 waves/CU (HW cap; VGPR=20
//       and 16.4KB LDS/block both allow it),
//   (b) 2-deep per-wave pipeline: double-buffered wave-private LDS region, so
//       each wave keeps TWO tiles' global loads outstanding. The ds_write of
//       stage A only waits (counted vmcnt) for A's loads; B's + next-A's stay
//       in flight across the consume phase.

#define BLOCK 256
#define NBLK  2048
#define WAVES_PER_BLOCK (BLOCK / 64)

__device__ __forceinline__ float row_loss(float p0, float p1, float p2,
                                          float p3, float p4,
                                          float t0, float t1, float t2) {
    float d0 = p0 - t0, d1 = p1 - t1, d2 = p2 - t2;
    float acc = d0 * d0 + d1 * d1 + d2 * d2;
    float tl = t2 * 0.95f;
    float tu = t2 * 1.05f;
    float pen = (p4 - t2) * 4.0f;
    float dl = p3 - tl;
    float du = p4 - tu;
    float lower = (p3 > p2) ? pen : ((p3 > tl) ? 0.0f : dl * dl);
    float upper = (p4 < p2) ? pen : ((p4 < tu) ? 0.0f : du * du);
    return acc + lower + upper;
}

__global__ __launch_bounds__(BLOCK) void ql_main(const float* __restrict__ preds,
                                                 const float* __restrict__ target,
                                                 double* __restrict__ ws,
                                                 long ntiles) {
    // per wave: 2 stages x (80 float4 preds + 48 float4 target) = 2x128 float4
    __shared__ float4 sbuf[WAVES_PER_BLOCK][2][128];
    __shared__ double wsum[WAVES_PER_BLOCK];

    const int lane = threadIdx.x & 63;
    const int w = threadIdx.x >> 6;
    const long gwave = (long)blockIdx.x * WAVES_PER_BLOCK + w;
    const long nw = (long)gridDim.x * WAVES_PER_BLOCK;

    const float4* pb4 = (const float4*)preds;
    const float4* tb4 = (const float4*)target;

    float* sp0 = (float*)&sbuf[w][0][0];    // 320 floats: preds rows, stride 5
    float* st0 = (float*)&sbuf[w][0][80];   // 192 floats: target rows, stride 3
    float* sp1 = (float*)&sbuf[w][1][0];
    float* st1 = (float*)&sbuf[w][1][80];

    // second-load LDS slot: lanes 0..15 -> preds float4 64..79,
    // lanes 16..63 -> target float4 0..47 (index select, single ds_write)
    const int slot = (lane < 16) ? (64 + lane) : (80 + (lane - 16));

    float acc = 0.0f;

    long ta = gwave;            // stage-A tile
    long tb = gwave + nw;       // stage-B tile
    bool ha = ta < ntiles;
    bool hb = tb < ntiles;
    float4 a0, a1, b0, b1;
    if (ha) {
        a0 = pb4[ta * 80 + lane];
        const float4* s = (lane < 16) ? (pb4 + ta * 80 + 64 + lane)
                                      : (tb4 + ta * 48 + (lane - 16));
        a1 = *s;
    }
    if (hb) {
        b0 = pb4[tb * 80 + lane];
        const float4* s = (lane < 16) ? (pb4 + tb * 80 + 64 + lane)
                                      : (tb4 + tb * 48 + (lane - 16));
        b1 = *s;
    }

    while (ha) {
        // ---- stage A: store regs -> LDS (waits only A's loads), refill A ----
        sbuf[w][0][lane] = a0;
        sbuf[w][0][slot] = a1;
        long tn = ta + 2 * nw;
        bool hn = tn < ntiles;
        if (hn) {
            a0 = pb4[tn * 80 + lane];
            const float4* s = (lane < 16) ? (pb4 + tn * 80 + 64 + lane)
                                          : (tb4 + tn * 48 + (lane - 16));
            a1 = *s;
        }
        // consume A: one row/lane; strides 5/3 -> conflict-free
        acc += row_loss(sp0[5 * lane + 0], sp0[5 * lane + 1], sp0[5 * lane + 2],
                        sp0[5 * lane + 3], sp0[5 * lane + 4],
                        st0[3 * lane + 0], st0[3 * lane + 1], st0[3 * lane + 2]);
        ta = tn;

        if (!hb) break;

        // ---- stage B ----
        sbuf[w][1][lane] = b0;
        sbuf[w][1][slot] = b1;
        long tm = tb + 2 * nw;
        bool hm = tm < ntiles;
        if (hm) {
            b0 = pb4[tm * 80 + lane];
            const float4* s = (lane < 16) ? (pb4 + tm * 80 + 64 + lane)
                                          : (tb4 + tm * 48 + (lane - 16));
            b1 = *s;
        }
        acc += row_loss(sp1[5 * lane + 0], sp1[5 * lane + 1], sp1[5 * lane + 2],
                        sp1[5 * lane + 3], sp1[5 * lane + 4],
                        st1[3 * lane + 0], st1[3 * lane + 1], st1[3 * lane + 2]);
        tb = tm;
        hb = hm;
        ha = hn;
    }

    // wave reduction (double), cross-wave via LDS, one plain store per block
    double dacc = (double)acc;
#pragma unroll
    for (int off = 32; off > 0; off >>= 1)
        dacc += __shfl_down(dacc, off, 64);
    if (lane == 0) wsum[w] = dacc;
    __syncthreads();
    if (threadIdx.x == 0)
        ws[blockIdx.x] = wsum[0] + wsum[1] + wsum[2] + wsum[3];
}

__global__ __launch_bounds__(256) void ql_finalize(const double* __restrict__ ws,
                                                   const float* __restrict__ preds,
                                                   const float* __restrict__ target,
                                                   float* __restrict__ out,
                                                   long rows, long tail_start) {
    __shared__ double wsum[4];
    const int tid = threadIdx.x;

    double d = 0.0;
#pragma unroll
    for (int i = 0; i < NBLK / 256; ++i)
        d += ws[tid + i * 256];

    // leftover rows not covered by full 64-row tiles (none for N=4194304)
    long r = tail_start + tid;
    if (r < rows) {
        const float* p = preds + r * 5;
        const float* tg = target + r * 3;
        d += (double)row_loss(p[0], p[1], p[2], p[3], p[4], tg[0], tg[1], tg[2]);
    }

#pragma unroll
    for (int off = 32; off > 0; off >>= 1)
        d += __shfl_down(d, off, 64);
    int lane = tid & 63, w = tid >> 6;
    if (lane == 0) wsum[w] = d;
    __syncthreads();
    if (tid == 0) {
        double total = wsum[0] + wsum[1] + wsum[2] + wsum[3];
        out[0] = (float)(total / ((double)rows * 5.0));
    }
}

extern "C" void kernel_launch(void* const* d_in, const int* in_sizes, int n_in,
                              void* d_out, int out_size, void* d_ws, size_t ws_size,
                              hipStream_t stream) {
    const float* preds = (const float*)d_in[0];
    const float* target = (const float*)d_in[1];
    long rows = (long)in_sizes[0] / 5;
    long ntiles = rows / 64;            // full 64-row tiles
    long tail_start = ntiles * 64;

    double* partials = (double*)d_ws;   // NBLK doubles = 16 KB

    ql_main<<<NBLK, BLOCK, 0, stream>>>(preds, target, partials, ntiles);
    ql_finalize<<<1, 256, 0, stream>>>(partials, preds, target,
                                       (float*)d_out, rows, tail_start);
}